// Round 1
// baseline (1971.035 us; speedup 1.0000x reference)
//
#include <hip/hip_runtime.h>
#include <math.h>

#define KCODES 1024
#define DIM 64
#define NTOT 131072          // 32*64*64 rows
#define QELEMS 8388608       // 32*64*64*64

// ws layout (floats): [0..1023] counts, [1024..66559] dw, [66560] sumsq, [66561..67584] enorm

__global__ __launch_bounds__(256) void vq_enorm_kernel(const float* __restrict__ embed,
                                                       float* __restrict__ enorm) {
    int k = blockIdx.x * 256 + threadIdx.x;
    if (k < KCODES) {
        const float4* e4 = (const float4*)(embed + (k << 6));
        float s = 0.f;
#pragma unroll
        for (int j = 0; j < 16; ++j) {
            float4 v = e4[j];
            s += v.x * v.x + v.y * v.y + v.z * v.z + v.w * v.w;
        }
        enorm[k] = s;
    }
}

// One block per (b,h): 64 pixels (w=0..63), D=64 channels.
__global__ __launch_bounds__(256) void vq_main_kernel(
    const float* __restrict__ in,      // [32][64][64][64] NCHW
    const float* __restrict__ embed,   // [1024][64]
    const float* __restrict__ enorm,   // [1024]
    float* __restrict__ out_quant,     // [32][64][64][64]
    float* __restrict__ out_idx,       // [131072] (as float)
    float* __restrict__ counts,        // [1024]
    float* __restrict__ dwacc,         // [1024][64]
    float* __restrict__ sumsq)         // [1]
{
    __shared__ float xs[64][68];      // [w][d], padded
    __shared__ float es[64][68];      // [code][d], padded
    __shared__ float en[KCODES];
    __shared__ float redv[64][16];
    __shared__ int   redi[64][16];
    __shared__ int   idxs[64];
    __shared__ float rsum[256];

    const int t   = threadIdx.x;
    const int blk = blockIdx.x;       // 0..2047
    const int b   = blk >> 6;
    const int h   = blk & 63;
    const float* xbase = in + b * 262144 + h * 64;   // + d*4096 + w

    // stage enorm
    for (int i = t; i < KCODES; i += 256) en[i] = enorm[i];

    // stage x tile: xs[w][d]
    {
        int w  = t & 63;
        int d0 = t >> 6;              // 0..3
#pragma unroll
        for (int j = 0; j < 16; ++j) {
            int d = d0 + (j << 2);
            xs[w][d] = xbase[d * 4096 + w];
        }
    }
    __syncthreads();

    const int r0 = (t >> 4) << 2;     // row group base (4 rows)
    const int cg = t & 15;            // code group (4 codes per stage)
    float minv[4] = {3.4e38f, 3.4e38f, 3.4e38f, 3.4e38f};
    int   mini[4] = {0, 0, 0, 0};

    for (int stage = 0; stage < 16; ++stage) {
        const int kbase = stage << 6;
        // stage 64 codes into es (coalesced float4)
        {
            const float4* eb4 = (const float4*)(embed + (kbase << 6));
#pragma unroll
            for (int j = 0; j < 4; ++j) {
                int q = t + (j << 8);          // 0..1023
                int c = q >> 4, dq = q & 15;
                *((float4*)&es[c][0] + dq) = eb4[q];
            }
        }
        __syncthreads();

        float acc[4][4];
#pragma unroll
        for (int i = 0; i < 4; ++i)
#pragma unroll
            for (int j = 0; j < 4; ++j) acc[i][j] = 0.f;

        const float4* xr0 = (const float4*)&xs[r0 + 0][0];
        const float4* xr1 = (const float4*)&xs[r0 + 1][0];
        const float4* xr2 = (const float4*)&xs[r0 + 2][0];
        const float4* xr3 = (const float4*)&xs[r0 + 3][0];
        const int c0 = cg << 2;
        const float4* ec0 = (const float4*)&es[c0 + 0][0];
        const float4* ec1 = (const float4*)&es[c0 + 1][0];
        const float4* ec2 = (const float4*)&es[c0 + 2][0];
        const float4* ec3 = (const float4*)&es[c0 + 3][0];

#pragma unroll
        for (int d4 = 0; d4 < 16; ++d4) {
            float4 x0 = xr0[d4], x1 = xr1[d4], x2 = xr2[d4], x3 = xr3[d4];
            float4 e0 = ec0[d4], e1 = ec1[d4], e2 = ec2[d4], e3 = ec3[d4];
            acc[0][0] += x0.x*e0.x + x0.y*e0.y + x0.z*e0.z + x0.w*e0.w;
            acc[0][1] += x0.x*e1.x + x0.y*e1.y + x0.z*e1.z + x0.w*e1.w;
            acc[0][2] += x0.x*e2.x + x0.y*e2.y + x0.z*e2.z + x0.w*e2.w;
            acc[0][3] += x0.x*e3.x + x0.y*e3.y + x0.z*e3.z + x0.w*e3.w;
            acc[1][0] += x1.x*e0.x + x1.y*e0.y + x1.z*e0.z + x1.w*e0.w;
            acc[1][1] += x1.x*e1.x + x1.y*e1.y + x1.z*e1.z + x1.w*e1.w;
            acc[1][2] += x1.x*e2.x + x1.y*e2.y + x1.z*e2.z + x1.w*e2.w;
            acc[1][3] += x1.x*e3.x + x1.y*e3.y + x1.z*e3.z + x1.w*e3.w;
            acc[2][0] += x2.x*e0.x + x2.y*e0.y + x2.z*e0.z + x2.w*e0.w;
            acc[2][1] += x2.x*e1.x + x2.y*e1.y + x2.z*e1.z + x2.w*e1.w;
            acc[2][2] += x2.x*e2.x + x2.y*e2.y + x2.z*e2.z + x2.w*e2.w;
            acc[2][3] += x2.x*e3.x + x2.y*e3.y + x2.z*e3.z + x2.w*e3.w;
            acc[3][0] += x3.x*e0.x + x3.y*e0.y + x3.z*e0.z + x3.w*e0.w;
            acc[3][1] += x3.x*e1.x + x3.y*e1.y + x3.z*e1.z + x3.w*e1.w;
            acc[3][2] += x3.x*e2.x + x3.y*e2.y + x3.z*e2.z + x3.w*e2.w;
            acc[3][3] += x3.x*e3.x + x3.y*e3.y + x3.z*e3.z + x3.w*e3.w;
        }

#pragma unroll
        for (int i = 0; i < 4; ++i)
#pragma unroll
            for (int j = 0; j < 4; ++j) {
                int code = kbase + c0 + j;
                float dist = en[code] - 2.0f * acc[i][j];
                if (dist < minv[i]) { minv[i] = dist; mini[i] = code; }
            }
        __syncthreads();
    }

    // cross-group argmin reduction
#pragma unroll
    for (int i = 0; i < 4; ++i) {
        redv[r0 + i][cg] = minv[i];
        redi[r0 + i][cg] = mini[i];
    }
    __syncthreads();
    if (t < 64) {
        float bv = redv[t][0];
        int   bi = redi[t][0];
#pragma unroll
        for (int g = 1; g < 16; ++g) {
            float v = redv[t][g];
            int   i = redi[t][g];
            if (v < bv || (v == bv && i < bi)) { bv = v; bi = i; }
        }
        idxs[t] = bi;
        out_idx[(blk << 6) + t] = (float)bi;
        atomicAdd(&counts[bi], 1.0f);
    }
    __syncthreads();

    // epilogue: quant write, (q-x)^2, dw scatter
    {
        int w  = t & 63;
        int cq = (t >> 6) << 4;        // 0,16,32,48
        int k  = idxs[w];
        const float4* eq = (const float4*)(embed + (k << 6) + cq);
        float* ob = out_quant + b * 262144 + h * 64 + w;
        float lsum = 0.f;
#pragma unroll
        for (int j = 0; j < 4; ++j) {
            float4 q = eq[j];
            float4 x = *((const float4*)&xs[w][0] + (cq >> 2) + j);
            float dx = q.x - x.x, dy = q.y - x.y, dz = q.z - x.z, dv = q.w - x.w;
            int c = cq + (j << 2);
            ob[(c + 0) * 4096] = x.x + dx;
            ob[(c + 1) * 4096] = x.y + dy;
            ob[(c + 2) * 4096] = x.z + dz;
            ob[(c + 3) * 4096] = x.w + dv;
            lsum += dx * dx + dy * dy + dz * dz + dv * dv;
            atomicAdd(&dwacc[(k << 6) + c + 0], x.x);
            atomicAdd(&dwacc[(k << 6) + c + 1], x.y);
            atomicAdd(&dwacc[(k << 6) + c + 2], x.z);
            atomicAdd(&dwacc[(k << 6) + c + 3], x.w);
        }
        rsum[t] = lsum;
    }
    __syncthreads();
    for (int s = 128; s > 0; s >>= 1) {
        if (t < s) rsum[t] += rsum[t + s];
        __syncthreads();
    }
    if (t == 0) atomicAdd(sumsq, rsum[0]);
}

__global__ __launch_bounds__(256) void vq_finalize_kernel(
    const float* __restrict__ ema_cs,   // [1024]
    const float* __restrict__ ema_w,    // [1024][64]
    const float* __restrict__ counts,
    const float* __restrict__ dwacc,
    const float* __restrict__ sumsq,
    float* __restrict__ out)
{
    const int t = threadIdx.x;
    float* o_loss  = out + QELEMS;
    float* o_perp  = out + QELEMS + 1;
    float* o_ncs   = out + QELEMS + 2 + NTOT;            // 8519682
    float* o_emaw  = o_ncs + KCODES;
    float* o_embed = o_emaw + KCODES * DIM;

    __shared__ float ncs_s[KCODES];
    __shared__ float red1[256];
    __shared__ float red2[256];

    float nsum = 0.f, ent = 0.f;
    for (int k = t; k < KCODES; k += 256) {
        float c   = counts[k];
        float ncs = 0.99f * ema_cs[k] + 0.01f * c;
        ncs_s[k] = ncs;
        o_ncs[k] = ncs;
        nsum += ncs;
        float p = c / (float)NTOT;
        ent += p * logf(p + 1e-10f);
    }
    red1[t] = nsum;
    red2[t] = ent;
    __syncthreads();
    for (int s = 128; s > 0; s >>= 1) {
        if (t < s) { red1[t] += red1[t + s]; red2[t] += red2[t + s]; }
        __syncthreads();
    }
    if (t == 0) {
        o_perp[0] = expf(-red2[0]);
        o_loss[0] = 0.25f * sumsq[0] / (float)QELEMS;
    }
    float n = red1[0];
    float denom = n + (float)KCODES * 1e-5f;
    for (int i = t; i < KCODES * DIM; i += 256) {
        int k = i >> 6;
        float cs = (ncs_s[k] + 1e-5f) / denom * n;
        cs = fmaxf(cs, 1e-5f);
        float w = 0.99f * ema_w[i] + 0.01f * dwacc[i];
        o_emaw[i]  = w;
        o_embed[i] = w / cs;
    }
}

extern "C" void kernel_launch(void* const* d_in, const int* in_sizes, int n_in,
                              void* d_out, int out_size, void* d_ws, size_t ws_size,
                              hipStream_t stream) {
    const float* in     = (const float*)d_in[0];
    const float* embed  = (const float*)d_in[1];
    const float* ema_cs = (const float*)d_in[2];
    const float* ema_w  = (const float*)d_in[3];
    float* out = (float*)d_out;
    float* ws  = (float*)d_ws;

    float* counts = ws;                 // 1024
    float* dwacc  = ws + 1024;          // 65536
    float* sumsq  = ws + 66560;         // 1
    float* enorm  = ws + 66561;         // 1024

    hipMemsetAsync(d_ws, 0, (size_t)66561 * sizeof(float), stream);
    vq_enorm_kernel<<<4, 256, 0, stream>>>(embed, enorm);
    vq_main_kernel<<<2048, 256, 0, stream>>>(in, embed, enorm,
                                             out, out + QELEMS + 2,
                                             counts, dwacc, sumsq);
    vq_finalize_kernel<<<1, 256, 0, stream>>>(ema_cs, ema_w, counts, dwacc, sumsq, out);
}

// Round 2
// 838.877 us; speedup vs baseline: 2.3496x; 2.3496x over previous
//
#include <hip/hip_runtime.h>
#include <math.h>

#define KCODES 1024
#define DIM 64
#define NTOT 131072          // 32*64*64 rows
#define QELEMS 8388608       // 32*64*64*64
#define XSTR 68              // padded row stride (floats)

// ws layout (floats): [0..1023] counts, [1024..66559] dw, [66560] sumsq, [66561..67584] enorm

__global__ __launch_bounds__(256) void vq_enorm_kernel(const float* __restrict__ embed,
                                                       float* __restrict__ enorm) {
    int k = blockIdx.x * 256 + threadIdx.x;
    if (k < KCODES) {
        const float4* e4 = (const float4*)(embed + (k << 6));
        float s = 0.f;
#pragma unroll
        for (int j = 0; j < 16; ++j) {
            float4 v = e4[j];
            s += v.x * v.x + v.y * v.y + v.z * v.z + v.w * v.w;
        }
        enorm[k] = s;
    }
}

// Kernel A: distances + argmin. One block per 128 pixels (b, h0..h0+1).
// 8x8 register tile per thread; rows p = rowg+16i, codes c = codeg+16j
// (stride-16 interleave -> es/xs b128 reads hit 8 bank groups, 2-way max).
__global__ __launch_bounds__(256, 2) void vq_argmin_kernel(
    const float* __restrict__ in,      // [32][64][64][64] NCHW
    const float* __restrict__ embed,   // [1024][64]
    const float* __restrict__ enorm,   // [1024]
    float* __restrict__ out_idx)       // [131072] (as float)
{
    __shared__ float xs[128 * XSTR];   // 34.8 KB
    __shared__ float es[128 * XSTR];   // 34.8 KB (reused for argmin reduction)
    __shared__ float en[KCODES];       // 4 KB

    const int t   = threadIdx.x;
    const int blk = blockIdx.x;        // 0..1023
    const int b   = blk >> 5;
    const int h0  = (blk & 31) << 1;
    const float* xb = in + b * 262144 + h0 * 64;   // + d*4096 + hw

    for (int i = t; i < KCODES; i += 256) en[i] = enorm[i];

    // stage x: 128 pixels x 64 dims, xs[p][d]
    {
        int hw = t & 127;
        int dh = t >> 7;               // 0 or 1
#pragma unroll
        for (int m = 0; m < 32; ++m) {
            int d = dh + (m << 1);
            xs[hw * XSTR + d] = xb[d * 4096 + hw];
        }
    }
    __syncthreads();

    const int rowg  = t & 15;
    const int codeg = t >> 4;
    float minv[8];
    int   mini[8];
#pragma unroll
    for (int i = 0; i < 8; ++i) { minv[i] = 3.4e38f; mini[i] = 0; }

    for (int tile = 0; tile < 8; ++tile) {
        // stage 128 codes (32 KB) into es[c][d]
        {
            const float4* eb = (const float4*)(embed + (tile << 13));
#pragma unroll
            for (int m = 0; m < 8; ++m) {
                int q = t + (m << 8);          // 0..2047
                int c = q >> 4, dq = q & 15;
                *(float4*)(es + c * XSTR + (dq << 2)) = eb[q];
            }
        }
        __syncthreads();

        float acc[8][8];
#pragma unroll
        for (int i = 0; i < 8; ++i)
#pragma unroll
            for (int j = 0; j < 8; ++j) acc[i][j] = 0.f;

#pragma unroll 2
        for (int d4 = 0; d4 < 16; ++d4) {
            float4 xv[8], ev[8];
#pragma unroll
            for (int i = 0; i < 8; ++i)
                xv[i] = *(const float4*)(xs + (rowg + (i << 4)) * XSTR + (d4 << 2));
#pragma unroll
            for (int j = 0; j < 8; ++j)
                ev[j] = *(const float4*)(es + (codeg + (j << 4)) * XSTR + (d4 << 2));
#pragma unroll
            for (int i = 0; i < 8; ++i)
#pragma unroll
                for (int j = 0; j < 8; ++j)
                    acc[i][j] += xv[i].x * ev[j].x + xv[i].y * ev[j].y
                               + xv[i].z * ev[j].z + xv[i].w * ev[j].w;
        }

        const int kbase = tile << 7;
#pragma unroll
        for (int j = 0; j < 8; ++j) {
            int c = kbase + codeg + (j << 4);
            float enc = en[c];
#pragma unroll
            for (int i = 0; i < 8; ++i) {
                float dist = enc - 2.0f * acc[i][j];
                if (dist < minv[i]) { minv[i] = dist; mini[i] = c; }
            }
        }
        __syncthreads();   // also protects es reuse below on last iter
    }

    // cross-codeg argmin reduction in reused es space: redv[codeg][p], redi
    float* redv = es;                       // 128*16 floats
    int*   redi = (int*)(es + 2048);        // 128*16 ints
#pragma unroll
    for (int i = 0; i < 8; ++i) {
        int p = rowg + (i << 4);
        redv[codeg * 128 + p] = minv[i];
        redi[codeg * 128 + p] = mini[i];
    }
    __syncthreads();
    if (t < 128) {
        float bv = redv[t];
        int   bi = redi[t];
#pragma unroll
        for (int g = 1; g < 16; ++g) {
            float v  = redv[g * 128 + t];
            int   ii = redi[g * 128 + t];
            if (v < bv || (v == bv && ii < bi)) { bv = v; bi = ii; }
        }
        out_idx[(blk << 7) + t] = (float)bi;
    }
}

// Kernel B: epilogue. One block per (b,h): 64 pixels.
__global__ __launch_bounds__(256) void vq_epilogue_kernel(
    const float* __restrict__ in,
    const float* __restrict__ embed,
    const float* __restrict__ idxf,    // [131072] as float
    float* __restrict__ out_quant,
    float* __restrict__ counts,
    float* __restrict__ dwacc,
    float* __restrict__ sumsq)
{
    __shared__ int   ks[64];
    __shared__ float rsum[256];
    const int t   = threadIdx.x;
    const int blk = blockIdx.x;        // 0..2047
    const int b   = blk >> 6;
    const int h   = blk & 63;

    if (t < 64) {
        int k = (int)idxf[(blk << 6) + t];
        ks[t] = k;
        atomicAdd(&counts[k], 1.0f);
    }
    __syncthreads();

    const int wg = t & 15, dq = t >> 4;
    const int w0 = wg << 2;
    const int k0 = ks[w0], k1 = ks[w0 + 1], k2 = ks[w0 + 2], k3 = ks[w0 + 3];
    const float* xb = in + b * 262144 + h * 64 + w0;
    float* ob = out_quant + b * 262144 + h * 64 + w0;
    float ls = 0.f;
#pragma unroll
    for (int dd = 0; dd < 4; ++dd) {
        int d = (dq << 2) + dd;
        float4 x = *(const float4*)(xb + d * 4096);
        float4 q;
        q.x = embed[(k0 << 6) + d];
        q.y = embed[(k1 << 6) + d];
        q.z = embed[(k2 << 6) + d];
        q.w = embed[(k3 << 6) + d];
        *(float4*)(ob + d * 4096) = q;
        float e0 = q.x - x.x, e1 = q.y - x.y, e2 = q.z - x.z, e3 = q.w - x.w;
        ls += e0 * e0 + e1 * e1 + e2 * e2 + e3 * e3;
        atomicAdd(&dwacc[(k0 << 6) + d], x.x);
        atomicAdd(&dwacc[(k1 << 6) + d], x.y);
        atomicAdd(&dwacc[(k2 << 6) + d], x.z);
        atomicAdd(&dwacc[(k3 << 6) + d], x.w);
    }
    rsum[t] = ls;
    __syncthreads();
    for (int s = 128; s > 0; s >>= 1) {
        if (t < s) rsum[t] += rsum[t + s];
        __syncthreads();
    }
    if (t == 0) atomicAdd(sumsq, rsum[0]);
}

__global__ __launch_bounds__(256) void vq_finalize_kernel(
    const float* __restrict__ ema_cs,
    const float* __restrict__ ema_w,
    const float* __restrict__ counts,
    const float* __restrict__ dwacc,
    const float* __restrict__ sumsq,
    float* __restrict__ out)
{
    const int t = threadIdx.x;
    float* o_loss  = out + QELEMS;
    float* o_perp  = out + QELEMS + 1;
    float* o_ncs   = out + QELEMS + 2 + NTOT;
    float* o_emaw  = o_ncs + KCODES;
    float* o_embed = o_emaw + KCODES * DIM;

    __shared__ float ncs_s[KCODES];
    __shared__ float red1[256];
    __shared__ float red2[256];

    float nsum = 0.f, ent = 0.f;
    for (int k = t; k < KCODES; k += 256) {
        float c   = counts[k];
        float ncs = 0.99f * ema_cs[k] + 0.01f * c;
        ncs_s[k] = ncs;
        o_ncs[k] = ncs;
        nsum += ncs;
        float p = c / (float)NTOT;
        ent += p * logf(p + 1e-10f);
    }
    red1[t] = nsum;
    red2[t] = ent;
    __syncthreads();
    for (int s = 128; s > 0; s >>= 1) {
        if (t < s) { red1[t] += red1[t + s]; red2[t] += red2[t + s]; }
        __syncthreads();
    }
    if (t == 0) {
        o_perp[0] = expf(-red2[0]);
        o_loss[0] = 0.25f * sumsq[0] / (float)QELEMS;
    }
    float n = red1[0];
    float denom = n + (float)KCODES * 1e-5f;
    for (int i = t; i < KCODES * DIM; i += 256) {
        int k = i >> 6;
        float cs = (ncs_s[k] + 1e-5f) / denom * n;
        cs = fmaxf(cs, 1e-5f);
        float w = 0.99f * ema_w[i] + 0.01f * dwacc[i];
        o_emaw[i]  = w;
        o_embed[i] = w / cs;
    }
}

extern "C" void kernel_launch(void* const* d_in, const int* in_sizes, int n_in,
                              void* d_out, int out_size, void* d_ws, size_t ws_size,
                              hipStream_t stream) {
    const float* in     = (const float*)d_in[0];
    const float* embed  = (const float*)d_in[1];
    const float* ema_cs = (const float*)d_in[2];
    const float* ema_w  = (const float*)d_in[3];
    float* out = (float*)d_out;
    float* ws  = (float*)d_ws;

    float* counts = ws;                 // 1024
    float* dwacc  = ws + 1024;          // 65536
    float* sumsq  = ws + 66560;         // 1
    float* enorm  = ws + 66561;         // 1024
    float* o_idx  = out + QELEMS + 2;   // indices (as float)

    hipMemsetAsync(d_ws, 0, (size_t)66561 * sizeof(float), stream);
    vq_enorm_kernel<<<4, 256, 0, stream>>>(embed, enorm);
    vq_argmin_kernel<<<1024, 256, 0, stream>>>(in, embed, enorm, o_idx);
    vq_epilogue_kernel<<<2048, 256, 0, stream>>>(in, embed, o_idx, out,
                                                 counts, dwacc, sumsq);
    vq_finalize_kernel<<<1, 256, 0, stream>>>(ema_cs, ema_w, counts, dwacc, sumsq, out);
}

// Round 3
// 800.597 us; speedup vs baseline: 2.4620x; 1.0478x over previous
//
#include <hip/hip_runtime.h>
#include <math.h>

#define KCODES 1024
#define DIM 64
#define NTOT 131072          // 32*64*64 rows
#define QELEMS 8388608       // 32*64*64*64
#define XSTR 68              // padded row stride (floats)

// ws layout (4B units):
//   0      counts_i [1024] int
//   1024   sumsq    [1]    float
//   1025   enorm    [1024] float
//   2052   cursor   [1024] int
//   3076   starts   [1025] int
//   4104   sorted   [131072] int
//   135176 dwacc    [65536] float

__global__ __launch_bounds__(256) void vq_enorm_kernel(const float* __restrict__ embed,
                                                       float* __restrict__ enorm) {
    int k = blockIdx.x * 256 + threadIdx.x;
    if (k < KCODES) {
        const float4* e4 = (const float4*)(embed + (k << 6));
        float s = 0.f;
#pragma unroll
        for (int j = 0; j < 16; ++j) {
            float4 v = e4[j];
            s += v.x * v.x + v.y * v.y + v.z * v.z + v.w * v.w;
        }
        enorm[k] = s;
    }
}

// Kernel A: distances + argmin + fused epilogue (quant write, sumsq, histogram).
// One block per 128 pixels (b, h0..h0+1). 8x8 register tile per thread.
__global__ __launch_bounds__(256, 2) void vq_argmin_kernel(
    const float* __restrict__ in,      // [32][64][64][64] NCHW
    const float* __restrict__ embed,   // [1024][64]
    const float* __restrict__ enorm,   // [1024]
    float* __restrict__ out_quant,     // [32][64][64][64]
    float* __restrict__ out_idx,       // [131072] (as float)
    int*   __restrict__ counts_i,      // [1024]
    float* __restrict__ sumsq)         // [1]
{
    __shared__ float xs[128 * XSTR];   // 34.8 KB
    __shared__ float es[128 * XSTR];   // 34.8 KB (reused after main loop)
    __shared__ float en[KCODES];       // 4 KB (reused as histogram)

    const int t   = threadIdx.x;
    const int blk = blockIdx.x;        // 0..1023
    const int b   = blk >> 5;
    const int h0  = (blk & 31) << 1;
    const float* xb = in + b * 262144 + h0 * 64;   // + d*4096 + hw

    for (int i = t; i < KCODES; i += 256) en[i] = enorm[i];

    // stage x: 128 pixels x 64 dims, xs[p][d]
    {
        int hw = t & 127;
        int dh = t >> 7;               // 0 or 1
#pragma unroll
        for (int m = 0; m < 32; ++m) {
            int d = dh + (m << 1);
            xs[hw * XSTR + d] = xb[d * 4096 + hw];
        }
    }
    __syncthreads();

    const int rowg  = t & 15;
    const int codeg = t >> 4;
    float minv[8];
    int   mini[8];
#pragma unroll
    for (int i = 0; i < 8; ++i) { minv[i] = 3.4e38f; mini[i] = 0; }

    for (int tile = 0; tile < 8; ++tile) {
        // stage 128 codes (32 KB) into es[c][d]
        {
            const float4* eb = (const float4*)(embed + (tile << 13));
#pragma unroll
            for (int m = 0; m < 8; ++m) {
                int q = t + (m << 8);          // 0..2047
                int c = q >> 4, dq = q & 15;
                *(float4*)(es + c * XSTR + (dq << 2)) = eb[q];
            }
        }
        __syncthreads();

        float acc[8][8];
#pragma unroll
        for (int i = 0; i < 8; ++i)
#pragma unroll
            for (int j = 0; j < 8; ++j) acc[i][j] = 0.f;

#pragma unroll 2
        for (int d4 = 0; d4 < 16; ++d4) {
            float4 xv[8], ev[8];
#pragma unroll
            for (int i = 0; i < 8; ++i)
                xv[i] = *(const float4*)(xs + (rowg + (i << 4)) * XSTR + (d4 << 2));
#pragma unroll
            for (int j = 0; j < 8; ++j)
                ev[j] = *(const float4*)(es + (codeg + (j << 4)) * XSTR + (d4 << 2));
#pragma unroll
            for (int i = 0; i < 8; ++i)
#pragma unroll
                for (int j = 0; j < 8; ++j)
                    acc[i][j] += xv[i].x * ev[j].x + xv[i].y * ev[j].y
                               + xv[i].z * ev[j].z + xv[i].w * ev[j].w;
        }

        const int kbase = tile << 7;
#pragma unroll
        for (int j = 0; j < 8; ++j) {
            int c = kbase + codeg + (j << 4);
            float enc = en[c];
#pragma unroll
            for (int i = 0; i < 8; ++i) {
                float dist = enc - 2.0f * acc[i][j];
                if (dist < minv[i]) { minv[i] = dist; mini[i] = c; }
            }
        }
        __syncthreads();
    }

    // ---- fused epilogue ----
    int*   hist   = (int*)en;               // 1024 ints (en dead now)
    float* redv   = es;                      // [16][128]
    int*   redi   = (int*)(es + 2048);       // [16][128]
    int*   idxs_s = (int*)(es + 4096);       // [128]
    float* rsum   = es + 4224;               // [256]

    for (int i = t; i < KCODES; i += 256) hist[i] = 0;
#pragma unroll
    for (int i = 0; i < 8; ++i) {
        int p = rowg + (i << 4);
        redv[codeg * 128 + p] = minv[i];
        redi[codeg * 128 + p] = mini[i];
    }
    __syncthreads();
    if (t < 128) {
        float bv = redv[t];
        int   bi = redi[t];
#pragma unroll
        for (int g = 1; g < 16; ++g) {
            float v  = redv[g * 128 + t];
            int   ii = redi[g * 128 + t];
            if (v < bv || (v == bv && ii < bi)) { bv = v; bi = ii; }
        }
        idxs_s[t] = bi;
        out_idx[(blk << 7) + t] = (float)bi;
        atomicAdd(&hist[bi], 1);
    }
    __syncthreads();
    for (int i = t; i < KCODES; i += 256) {
        int v = hist[i];
        if (v) atomicAdd(&counts_i[i], v);
    }

    // quant write + sumsq: hw = t&127, channels dh, dh+2, ...
    {
        int hw = t & 127;
        int dh = t >> 7;
        int k  = idxs_s[hw];
        const float* eq = embed + (k << 6);
        float* ob = out_quant + b * 262144 + h0 * 64 + hw;
        float ls = 0.f;
#pragma unroll
        for (int m = 0; m < 32; ++m) {
            int d = dh + (m << 1);
            float q = eq[d];
            float x = xs[hw * XSTR + d];
            ob[d * 4096] = q;
            float e = q - x;
            ls += e * e;
        }
        rsum[t] = ls;
    }
    __syncthreads();
    for (int s = 128; s > 0; s >>= 1) {
        if (t < s) rsum[t] += rsum[t + s];
        __syncthreads();
    }
    if (t == 0) atomicAdd(sumsq, rsum[0]);
}

// Kernel: exclusive scan of 1024 counts -> starts[1025], cursor copy.
__global__ __launch_bounds__(256) void vq_scan_kernel(const int* __restrict__ counts_i,
                                                      int* __restrict__ starts,
                                                      int* __restrict__ cursor) {
    __shared__ int part[256];
    int t = threadIdx.x;
    int4 c = *(const int4*)(counts_i + (t << 2));
    part[t] = c.x + c.y + c.z + c.w;
    __syncthreads();
    for (int off = 1; off < 256; off <<= 1) {
        int v   = part[t];
        int add = (t >= off) ? part[t - off] : 0;
        __syncthreads();
        part[t] = v + add;
        __syncthreads();
    }
    int excl = (t == 0) ? 0 : part[t - 1];
    int4 st;
    st.x = excl;
    st.y = st.x + c.x;
    st.z = st.y + c.y;
    st.w = st.z + c.z;
    *(int4*)(starts + (t << 2)) = st;
    *(int4*)(cursor + (t << 2)) = st;
    if (t == 255) starts[1024] = part[255];
}

// Kernel: bin rows by code.
__global__ __launch_bounds__(256) void vq_scatter_kernel(const float* __restrict__ idxf,
                                                         int* __restrict__ cursor,
                                                         int* __restrict__ sorted) {
    int i = blockIdx.x * 256 + threadIdx.x;
    int k = (int)idxf[i];
    int pos = atomicAdd(&cursor[k], 1);
    sorted[pos] = i;
}

// Kernel: per-code dw reduction, no atomics. One block per code; lane = channel.
__global__ __launch_bounds__(256) void vq_dw_kernel(const float* __restrict__ in,
                                                    const int* __restrict__ starts,
                                                    const int* __restrict__ sorted,
                                                    float* __restrict__ dwacc) {
    __shared__ float sacc[256];
    const int t  = threadIdx.x;
    const int k  = blockIdx.x;
    const int wv = t >> 6;
    const int d  = t & 63;
    const int s0 = starts[k], s1 = starts[k + 1];
    float acc = 0.f;
    for (int m = s0 + wv; m < s1; m += 4) {
        int r   = sorted[m];
        int b   = r >> 12;
        int rem = r & 4095;          // h*64 + w
        acc += in[b * 262144 + d * 4096 + rem];
    }
    sacc[t] = acc;
    __syncthreads();
    if (t < 64)
        dwacc[(k << 6) + t] = sacc[t] + sacc[64 + t] + sacc[128 + t] + sacc[192 + t];
}

__global__ __launch_bounds__(256) void vq_finalize_kernel(
    const float* __restrict__ ema_cs,
    const float* __restrict__ ema_w,
    const int*   __restrict__ counts_i,
    const float* __restrict__ dwacc,
    const float* __restrict__ sumsq,
    float* __restrict__ out)
{
    const int t = threadIdx.x;
    float* o_loss  = out + QELEMS;
    float* o_perp  = out + QELEMS + 1;
    float* o_ncs   = out + QELEMS + 2 + NTOT;
    float* o_emaw  = o_ncs + KCODES;
    float* o_embed = o_emaw + KCODES * DIM;

    __shared__ float ncs_s[KCODES];
    __shared__ float red1[256];
    __shared__ float red2[256];

    float nsum = 0.f, ent = 0.f;
    for (int k = t; k < KCODES; k += 256) {
        float c   = (float)counts_i[k];
        float ncs = 0.99f * ema_cs[k] + 0.01f * c;
        ncs_s[k] = ncs;
        o_ncs[k] = ncs;
        nsum += ncs;
        float p = c / (float)NTOT;
        ent += p * logf(p + 1e-10f);
    }
    red1[t] = nsum;
    red2[t] = ent;
    __syncthreads();
    for (int s = 128; s > 0; s >>= 1) {
        if (t < s) { red1[t] += red1[t + s]; red2[t] += red2[t + s]; }
        __syncthreads();
    }
    if (t == 0) {
        o_perp[0] = expf(-red2[0]);
        o_loss[0] = 0.25f * sumsq[0] / (float)QELEMS;
    }
    float n = red1[0];
    float denom = n + (float)KCODES * 1e-5f;
    for (int i = t; i < KCODES * DIM; i += 256) {
        int k = i >> 6;
        float cs = (ncs_s[k] + 1e-5f) / denom * n;
        cs = fmaxf(cs, 1e-5f);
        float w = 0.99f * ema_w[i] + 0.01f * dwacc[i];
        o_emaw[i]  = w;
        o_embed[i] = w / cs;
    }
}

extern "C" void kernel_launch(void* const* d_in, const int* in_sizes, int n_in,
                              void* d_out, int out_size, void* d_ws, size_t ws_size,
                              hipStream_t stream) {
    const float* in     = (const float*)d_in[0];
    const float* embed  = (const float*)d_in[1];
    const float* ema_cs = (const float*)d_in[2];
    const float* ema_w  = (const float*)d_in[3];
    float* out = (float*)d_out;
    float* ws  = (float*)d_ws;

    int*   counts_i = (int*)ws;              // 1024
    float* sumsq    = ws + 1024;             // 1
    float* enorm    = ws + 1025;             // 1024
    int*   cursor   = (int*)ws + 2052;       // 1024
    int*   starts   = (int*)ws + 3076;       // 1025
    int*   sorted   = (int*)ws + 4104;       // 131072
    float* dwacc    = ws + 135176;           // 65536
    float* o_idx    = out + QELEMS + 2;      // indices (as float)

    hipMemsetAsync(d_ws, 0, 1025 * sizeof(float), stream);   // counts + sumsq
    vq_enorm_kernel<<<4, 256, 0, stream>>>(embed, enorm);
    vq_argmin_kernel<<<1024, 256, 0, stream>>>(in, embed, enorm, out, o_idx,
                                               counts_i, sumsq);
    vq_scan_kernel<<<1, 256, 0, stream>>>(counts_i, starts, cursor);
    vq_scatter_kernel<<<512, 256, 0, stream>>>(o_idx, cursor, sorted);
    vq_dw_kernel<<<1024, 256, 0, stream>>>(in, starts, sorted, dwacc);
    vq_finalize_kernel<<<1, 256, 0, stream>>>(ema_cs, ema_w, counts_i, dwacc, sumsq, out);
}

// Round 4
// 638.754 us; speedup vs baseline: 3.0857x; 1.2534x over previous
//
#include <hip/hip_runtime.h>
#include <math.h>

#define KCODES 1024
#define DIM 64
#define NTOT 131072          // 32*64*64 rows
#define QELEMS 8388608       // 32*64*64*64
#define XSTR 68              // padded row stride (floats)

// ws layout (4B units):
//   0      counts_i [1024] int
//   1024   sumsq    [1]    float
//   1025   enorm    [1024] float
//   2052   cursor   [1024] int
//   3076   starts   [1025] int
//   4104   sorted   [131072] int
//   135176 dwacc    [65536] float
//   200712 flat_x   [8388608] float   (optional, if ws_size permits)
#define WS_FLAT_OFF 200712
#define WS_NEED_FLAT ((size_t)(WS_FLAT_OFF + QELEMS) * 4)

__global__ __launch_bounds__(256) void vq_enorm_kernel(const float* __restrict__ embed,
                                                       float* __restrict__ enorm) {
    int k = blockIdx.x * 256 + threadIdx.x;
    if (k < KCODES) {
        const float4* e4 = (const float4*)(embed + (k << 6));
        float s = 0.f;
#pragma unroll
        for (int j = 0; j < 16; ++j) {
            float4 v = e4[j];
            s += v.x * v.x + v.y * v.y + v.z * v.z + v.w * v.w;
        }
        enorm[k] = s;
    }
}

// Kernel A: distances + argmin + fused epilogue (quant write, sumsq, histogram,
// optional NHWC flat_x dump). One block per 128 pixels. 8x8 register tile.
__global__ __launch_bounds__(256, 2) void vq_argmin_kernel(
    const float* __restrict__ in,      // [32][64][64][64] NCHW
    const float* __restrict__ embed,   // [1024][64]
    const float* __restrict__ enorm,   // [1024]
    float* __restrict__ out_quant,     // [32][64][64][64]
    float* __restrict__ out_idx,       // [131072] (as float)
    int*   __restrict__ counts_i,      // [1024]
    float* __restrict__ sumsq,         // [1]
    float* __restrict__ flat_x)        // [131072][64] or nullptr
{
    __shared__ float xs[128 * XSTR];   // 34.8 KB
    __shared__ float es[128 * XSTR];   // 34.8 KB (reused after main loop)
    __shared__ float en[KCODES];       // 4 KB (reused as histogram)

    const int t   = threadIdx.x;
    const int blk = blockIdx.x;        // 0..1023
    const int b   = blk >> 5;
    const int h0  = (blk & 31) << 1;
    const float* xb = in + b * 262144 + h0 * 64;   // + d*4096 + hw

    for (int i = t; i < KCODES; i += 256) en[i] = enorm[i];

    // stage x: 128 pixels x 64 dims, xs[p][d]
    {
        int hw = t & 127;
        int dh = t >> 7;               // 0 or 1
#pragma unroll
        for (int m = 0; m < 32; ++m) {
            int d = dh + (m << 1);
            xs[hw * XSTR + d] = xb[d * 4096 + hw];
        }
    }

    // prefetch embed tile 0 into registers
    float4 pf[8];
    {
        const float4* eb = (const float4*)embed;
#pragma unroll
        for (int m = 0; m < 8; ++m) pf[m] = eb[t + (m << 8)];
    }
    __syncthreads();

    // NHWC dump (block's 128 rows are contiguous in flat order)
    if (flat_x) {
        int row = t >> 1, half = t & 1;
        const float* src = xs + row * XSTR + (half << 5);
        float* dst = flat_x + ((size_t)blk << 13) + (row << 6) + (half << 5);
#pragma unroll
        for (int j = 0; j < 8; ++j)
            *(float4*)(dst + (j << 2)) = *(const float4*)(src + (j << 2));
    }

    const int rowg  = t & 15;
    const int codeg = t >> 4;
    float minv[8];
    int   mini[8];
#pragma unroll
    for (int i = 0; i < 8; ++i) { minv[i] = 3.4e38f; mini[i] = 0; }

    for (int tile = 0; tile < 8; ++tile) {
        // write prefetched tile into es[c][d]
#pragma unroll
        for (int m = 0; m < 8; ++m) {
            int q = t + (m << 8);          // 0..2047
            int c = q >> 4, dq = q & 15;
            *(float4*)(es + c * XSTR + (dq << 2)) = pf[m];
        }
        __syncthreads();

        if (tile < 7) {
            const float4* ebn = (const float4*)(embed + ((tile + 1) << 13));
#pragma unroll
            for (int m = 0; m < 8; ++m) pf[m] = ebn[t + (m << 8)];
        }

        float acc[8][8];
#pragma unroll
        for (int i = 0; i < 8; ++i)
#pragma unroll
            for (int j = 0; j < 8; ++j) acc[i][j] = 0.f;

#pragma unroll 2
        for (int d4 = 0; d4 < 16; ++d4) {
            float4 xv[8], ev[8];
#pragma unroll
            for (int i = 0; i < 8; ++i)
                xv[i] = *(const float4*)(xs + (rowg + (i << 4)) * XSTR + (d4 << 2));
#pragma unroll
            for (int j = 0; j < 8; ++j)
                ev[j] = *(const float4*)(es + (codeg + (j << 4)) * XSTR + (d4 << 2));
#pragma unroll
            for (int i = 0; i < 8; ++i)
#pragma unroll
                for (int j = 0; j < 8; ++j)
                    acc[i][j] += xv[i].x * ev[j].x + xv[i].y * ev[j].y
                               + xv[i].z * ev[j].z + xv[i].w * ev[j].w;
        }

        const int kbase = tile << 7;
#pragma unroll
        for (int j = 0; j < 8; ++j) {
            int c = kbase + codeg + (j << 4);
            float enc = en[c];
#pragma unroll
            for (int i = 0; i < 8; ++i) {
                float dist = enc - 2.0f * acc[i][j];
                if (dist < minv[i]) { minv[i] = dist; mini[i] = c; }
            }
        }
        __syncthreads();
    }

    // ---- fused epilogue ----
    int*   hist   = (int*)en;               // 1024 ints (en dead now)
    float* redv   = es;                      // [16][128]
    int*   redi   = (int*)(es + 2048);       // [16][128]
    int*   idxs_s = (int*)(es + 4096);       // [128]
    float* rsum   = es + 4224;               // [256]

    for (int i = t; i < KCODES; i += 256) hist[i] = 0;
#pragma unroll
    for (int i = 0; i < 8; ++i) {
        int p = rowg + (i << 4);
        redv[codeg * 128 + p] = minv[i];
        redi[codeg * 128 + p] = mini[i];
    }
    __syncthreads();
    if (t < 128) {
        float bv = redv[t];
        int   bi = redi[t];
#pragma unroll
        for (int g = 1; g < 16; ++g) {
            float v  = redv[g * 128 + t];
            int   ii = redi[g * 128 + t];
            if (v < bv || (v == bv && ii < bi)) { bv = v; bi = ii; }
        }
        idxs_s[t] = bi;
        out_idx[(blk << 7) + t] = (float)bi;
        atomicAdd(&hist[bi], 1);
    }
    __syncthreads();
    for (int i = t; i < KCODES; i += 256) {
        int v = hist[i];
        if (v) atomicAdd(&counts_i[i], v);
    }

    // quant write + sumsq
    {
        int hw = t & 127;
        int dh = t >> 7;
        int k  = idxs_s[hw];
        const float* eq = embed + (k << 6);
        float* ob = out_quant + b * 262144 + h0 * 64 + hw;
        float ls = 0.f;
#pragma unroll
        for (int m = 0; m < 32; ++m) {
            int d = dh + (m << 1);
            float q = eq[d];
            float x = xs[hw * XSTR + d];
            ob[d * 4096] = q;
            float e = q - x;
            ls += e * e;
        }
        rsum[t] = ls;
    }
    __syncthreads();
    for (int s = 128; s > 0; s >>= 1) {
        if (t < s) rsum[t] += rsum[t + s];
        __syncthreads();
    }
    if (t == 0) atomicAdd(sumsq, rsum[0]);
}

// exclusive scan of 1024 counts -> starts[1025], cursor copy.
__global__ __launch_bounds__(256) void vq_scan_kernel(const int* __restrict__ counts_i,
                                                      int* __restrict__ starts,
                                                      int* __restrict__ cursor) {
    __shared__ int part[256];
    int t = threadIdx.x;
    int4 c = *(const int4*)(counts_i + (t << 2));
    part[t] = c.x + c.y + c.z + c.w;
    __syncthreads();
    for (int off = 1; off < 256; off <<= 1) {
        int v   = part[t];
        int add = (t >= off) ? part[t - off] : 0;
        __syncthreads();
        part[t] = v + add;
        __syncthreads();
    }
    int excl = (t == 0) ? 0 : part[t - 1];
    int4 st;
    st.x = excl;
    st.y = st.x + c.x;
    st.z = st.y + c.y;
    st.w = st.z + c.z;
    *(int4*)(starts + (t << 2)) = st;
    *(int4*)(cursor + (t << 2)) = st;
    if (t == 255) starts[1024] = part[255];
}

__global__ __launch_bounds__(256) void vq_scatter_kernel(const float* __restrict__ idxf,
                                                         int* __restrict__ cursor,
                                                         int* __restrict__ sorted) {
    int i = blockIdx.x * 256 + threadIdx.x;
    int k = (int)idxf[i];
    int pos = atomicAdd(&cursor[k], 1);
    sorted[pos] = i;
}

// dw reduce from NHWC flat_x: one block per code; lane = channel; coalesced 256B rows.
__global__ __launch_bounds__(256) void vq_dw_flat_kernel(const float* __restrict__ flat_x,
                                                         const int* __restrict__ starts,
                                                         const int* __restrict__ sorted,
                                                         float* __restrict__ dwacc) {
    __shared__ float sacc[256];
    const int t  = threadIdx.x;
    const int k  = blockIdx.x;
    const int wv = t >> 6;
    const int d  = t & 63;
    const int s0 = starts[k], s1 = starts[k + 1];
    float a0 = 0.f, a1 = 0.f;
    int m = s0 + wv;
    for (; m + 4 < s1; m += 8) {
        int r0 = sorted[m], r1 = sorted[m + 4];
        a0 += flat_x[((size_t)r0 << 6) + d];
        a1 += flat_x[((size_t)r1 << 6) + d];
    }
    if (m < s1) a0 += flat_x[((size_t)sorted[m] << 6) + d];
    sacc[t] = a0 + a1;
    __syncthreads();
    if (t < 64)
        dwacc[(k << 6) + t] = sacc[t] + sacc[64 + t] + sacc[128 + t] + sacc[192 + t];
}

// fallback: gather from NCHW (uncoalesced) if ws too small for flat_x.
__global__ __launch_bounds__(256) void vq_dw_nchw_kernel(const float* __restrict__ in,
                                                         const int* __restrict__ starts,
                                                         const int* __restrict__ sorted,
                                                         float* __restrict__ dwacc) {
    __shared__ float sacc[256];
    const int t  = threadIdx.x;
    const int k  = blockIdx.x;
    const int wv = t >> 6;
    const int d  = t & 63;
    const int s0 = starts[k], s1 = starts[k + 1];
    float acc = 0.f;
    for (int m = s0 + wv; m < s1; m += 4) {
        int r   = sorted[m];
        int b   = r >> 12;
        int rem = r & 4095;
        acc += in[b * 262144 + d * 4096 + rem];
    }
    sacc[t] = acc;
    __syncthreads();
    if (t < 64)
        dwacc[(k << 6) + t] = sacc[t] + sacc[64 + t] + sacc[128 + t] + sacc[192 + t];
}

__global__ __launch_bounds__(256) void vq_finalize_kernel(
    const float* __restrict__ ema_cs,
    const float* __restrict__ ema_w,
    const int*   __restrict__ counts_i,
    const float* __restrict__ dwacc,
    const float* __restrict__ sumsq,
    float* __restrict__ out)
{
    const int t = threadIdx.x;
    float* o_loss  = out + QELEMS;
    float* o_perp  = out + QELEMS + 1;
    float* o_ncs   = out + QELEMS + 2 + NTOT;
    float* o_emaw  = o_ncs + KCODES;
    float* o_embed = o_emaw + KCODES * DIM;

    __shared__ float ncs_s[KCODES];
    __shared__ float red1[256];
    __shared__ float red2[256];

    float nsum = 0.f, ent = 0.f;
    for (int k = t; k < KCODES; k += 256) {
        float c   = (float)counts_i[k];
        float ncs = 0.99f * ema_cs[k] + 0.01f * c;
        ncs_s[k] = ncs;
        o_ncs[k] = ncs;
        nsum += ncs;
        float p = c / (float)NTOT;
        ent += p * logf(p + 1e-10f);
    }
    red1[t] = nsum;
    red2[t] = ent;
    __syncthreads();
    for (int s = 128; s > 0; s >>= 1) {
        if (t < s) { red1[t] += red1[t + s]; red2[t] += red2[t + s]; }
        __syncthreads();
    }
    if (t == 0) {
        o_perp[0] = expf(-red2[0]);
        o_loss[0] = 0.25f * sumsq[0] / (float)QELEMS;
    }
    float n = red1[0];
    float denom = n + (float)KCODES * 1e-5f;
    for (int i = t; i < KCODES * DIM; i += 256) {
        int k = i >> 6;
        float cs = (ncs_s[k] + 1e-5f) / denom * n;
        cs = fmaxf(cs, 1e-5f);
        float w = 0.99f * ema_w[i] + 0.01f * dwacc[i];
        o_emaw[i]  = w;
        o_embed[i] = w / cs;
    }
}

extern "C" void kernel_launch(void* const* d_in, const int* in_sizes, int n_in,
                              void* d_out, int out_size, void* d_ws, size_t ws_size,
                              hipStream_t stream) {
    const float* in     = (const float*)d_in[0];
    const float* embed  = (const float*)d_in[1];
    const float* ema_cs = (const float*)d_in[2];
    const float* ema_w  = (const float*)d_in[3];
    float* out = (float*)d_out;
    float* ws  = (float*)d_ws;

    int*   counts_i = (int*)ws;              // 1024
    float* sumsq    = ws + 1024;             // 1
    float* enorm    = ws + 1025;             // 1024
    int*   cursor   = (int*)ws + 2052;       // 1024
    int*   starts   = (int*)ws + 3076;       // 1025
    int*   sorted   = (int*)ws + 4104;       // 131072
    float* dwacc    = ws + 135176;           // 65536
    const bool use_flat = ws_size >= WS_NEED_FLAT;
    float* flat_x   = use_flat ? (ws + WS_FLAT_OFF) : (float*)0;
    float* o_idx    = out + QELEMS + 2;      // indices (as float)

    hipMemsetAsync(d_ws, 0, 1025 * sizeof(float), stream);   // counts + sumsq
    vq_enorm_kernel<<<4, 256, 0, stream>>>(embed, enorm);
    vq_argmin_kernel<<<1024, 256, 0, stream>>>(in, embed, enorm, out, o_idx,
                                               counts_i, sumsq, flat_x);
    vq_scan_kernel<<<1, 256, 0, stream>>>(counts_i, starts, cursor);
    vq_scatter_kernel<<<512, 256, 0, stream>>>(o_idx, cursor, sorted);
    if (use_flat)
        vq_dw_flat_kernel<<<1024, 256, 0, stream>>>(flat_x, starts, sorted, dwacc);
    else
        vq_dw_nchw_kernel<<<1024, 256, 0, stream>>>(in, starts, sorted, dwacc);
    vq_finalize_kernel<<<1, 256, 0, stream>>>(ema_cs, ema_w, counts_i, dwacc, sumsq, out);
}

// Round 5
// 631.200 us; speedup vs baseline: 3.1227x; 1.0120x over previous
//
#include <hip/hip_runtime.h>
#include <hip/hip_cooperative_groups.h>
#include <math.h>

namespace cg = cooperative_groups;

#define KCODES 1024
#define DIM 64
#define NTOT 131072          // 32*64*64 rows
#define QELEMS 8388608       // 32*64*64*64
#define XSTR 68              // padded row stride (floats)

// ws layout (4B units):
//   0..1023    counts_i [1024] int
//   1024       sumsq
//   1025       nsum
//   1026       ent
//   1027..2050 cursor [1024] int
//   2052..3075 enorm  [1024] float
//   4104..135175 sorted [131072] int
//   200712..   flat_x [8388608] float (optional)
#define WS_FLAT_OFF 200712
#define WS_NEED_FLAT ((size_t)(WS_FLAT_OFF + QELEMS) * 4)

__global__ __launch_bounds__(256) void vq_enorm_kernel(const float* __restrict__ embed,
                                                       float* __restrict__ enorm) {
    int k = blockIdx.x * 256 + threadIdx.x;
    if (k < KCODES) {
        const float4* e4 = (const float4*)(embed + (k << 6));
        float s = 0.f;
#pragma unroll
        for (int j = 0; j < 16; ++j) {
            float4 v = e4[j];
            s += v.x * v.x + v.y * v.y + v.z * v.z + v.w * v.w;
        }
        enorm[k] = s;
    }
}

// Kernel A: distances + argmin + fused epilogue (quant write, sumsq, histogram,
// NHWC flat_x dump). One block per 128 pixels. 8x8 register tile.
__global__ __launch_bounds__(256, 2) void vq_argmin_kernel(
    const float* __restrict__ in,      // [32][64][64][64] NCHW
    const float* __restrict__ embed,   // [1024][64]
    const float* __restrict__ enorm,   // [1024]
    float* __restrict__ out_quant,     // [32][64][64][64]
    float* __restrict__ out_idx,       // [131072] (as float)
    int*   __restrict__ counts_i,      // [1024]
    float* __restrict__ sumsq,         // [1]
    float* __restrict__ flat_x)        // [131072][64] or nullptr
{
    __shared__ float xs[128 * XSTR];   // 34.8 KB
    __shared__ float es[128 * XSTR];   // 34.8 KB (reused after main loop)
    __shared__ float en[KCODES];       // 4 KB (reused as histogram)

    const int t   = threadIdx.x;
    const int blk = blockIdx.x;        // 0..1023
    const int b   = blk >> 5;
    const int h0  = (blk & 31) << 1;
    const float* xb = in + b * 262144 + h0 * 64;

    for (int i = t; i < KCODES; i += 256) en[i] = enorm[i];

    {
        int hw = t & 127;
        int dh = t >> 7;
#pragma unroll
        for (int m = 0; m < 32; ++m) {
            int d = dh + (m << 1);
            xs[hw * XSTR + d] = xb[d * 4096 + hw];
        }
    }

    float4 pf[8];
    {
        const float4* eb = (const float4*)embed;
#pragma unroll
        for (int m = 0; m < 8; ++m) pf[m] = eb[t + (m << 8)];
    }
    __syncthreads();

    if (flat_x) {
        int row = t >> 1, half = t & 1;
        const float* src = xs + row * XSTR + (half << 5);
        float* dst = flat_x + ((size_t)blk << 13) + (row << 6) + (half << 5);
#pragma unroll
        for (int j = 0; j < 8; ++j)
            *(float4*)(dst + (j << 2)) = *(const float4*)(src + (j << 2));
    }

    const int rowg  = t & 15;
    const int codeg = t >> 4;
    float minv[8];
    int   mini[8];
#pragma unroll
    for (int i = 0; i < 8; ++i) { minv[i] = 3.4e38f; mini[i] = 0; }

    for (int tile = 0; tile < 8; ++tile) {
#pragma unroll
        for (int m = 0; m < 8; ++m) {
            int q = t + (m << 8);
            int c = q >> 4, dq = q & 15;
            *(float4*)(es + c * XSTR + (dq << 2)) = pf[m];
        }
        __syncthreads();

        if (tile < 7) {
            const float4* ebn = (const float4*)(embed + ((tile + 1) << 13));
#pragma unroll
            for (int m = 0; m < 8; ++m) pf[m] = ebn[t + (m << 8)];
        }

        float acc[8][8];
#pragma unroll
        for (int i = 0; i < 8; ++i)
#pragma unroll
            for (int j = 0; j < 8; ++j) acc[i][j] = 0.f;

#pragma unroll 2
        for (int d4 = 0; d4 < 16; ++d4) {
            float4 xv[8], ev[8];
#pragma unroll
            for (int i = 0; i < 8; ++i)
                xv[i] = *(const float4*)(xs + (rowg + (i << 4)) * XSTR + (d4 << 2));
#pragma unroll
            for (int j = 0; j < 8; ++j)
                ev[j] = *(const float4*)(es + (codeg + (j << 4)) * XSTR + (d4 << 2));
#pragma unroll
            for (int i = 0; i < 8; ++i)
#pragma unroll
                for (int j = 0; j < 8; ++j)
                    acc[i][j] += xv[i].x * ev[j].x + xv[i].y * ev[j].y
                               + xv[i].z * ev[j].z + xv[i].w * ev[j].w;
        }

        const int kbase = tile << 7;
#pragma unroll
        for (int j = 0; j < 8; ++j) {
            int c = kbase + codeg + (j << 4);
            float enc = en[c];
#pragma unroll
            for (int i = 0; i < 8; ++i) {
                float dist = enc - 2.0f * acc[i][j];
                if (dist < minv[i]) { minv[i] = dist; mini[i] = c; }
            }
        }
        __syncthreads();
    }

    // ---- fused epilogue ----
    int*   hist   = (int*)en;
    float* redv   = es;
    int*   redi   = (int*)(es + 2048);
    int*   idxs_s = (int*)(es + 4096);
    float* rsum   = es + 4224;

    for (int i = t; i < KCODES; i += 256) hist[i] = 0;
#pragma unroll
    for (int i = 0; i < 8; ++i) {
        int p = rowg + (i << 4);
        redv[codeg * 128 + p] = minv[i];
        redi[codeg * 128 + p] = mini[i];
    }
    __syncthreads();
    if (t < 128) {
        float bv = redv[t];
        int   bi = redi[t];
#pragma unroll
        for (int g = 1; g < 16; ++g) {
            float v  = redv[g * 128 + t];
            int   ii = redi[g * 128 + t];
            if (v < bv || (v == bv && ii < bi)) { bv = v; bi = ii; }
        }
        idxs_s[t] = bi;
        out_idx[(blk << 7) + t] = (float)bi;
        atomicAdd(&hist[bi], 1);
    }
    __syncthreads();
    for (int i = t; i < KCODES; i += 256) {
        int v = hist[i];
        if (v) atomicAdd(&counts_i[i], v);
    }

    {
        int hw = t & 127;
        int dh = t >> 7;
        int k  = idxs_s[hw];
        const float* eq = embed + (k << 6);
        float* ob = out_quant + b * 262144 + h0 * 64 + hw;
        float ls = 0.f;
#pragma unroll
        for (int m = 0; m < 32; ++m) {
            int d = dh + (m << 1);
            float q = eq[d];
            float x = xs[hw * XSTR + d];
            ob[d * 4096] = q;
            float e = q - x;
            ls += e * e;
        }
        rsum[t] = ls;
    }
    __syncthreads();
    for (int s = 128; s > 0; s >>= 1) {
        if (t < s) rsum[t] += rsum[t + s];
        __syncthreads();
    }
    if (t == 0) atomicAdd(sumsq, rsum[0]);
}

// Fused cooperative tail: scan + LDS-aggregated scatter + dw gather + finalize.
// 256 blocks x 256 threads. Each block: 512 rows (scatter), 4 codes (dw/EMA).
__global__ __launch_bounds__(256) void vq_tail_kernel(
    const float* __restrict__ in,       // NCHW fallback
    const float* __restrict__ flat_x,   // [N][64] or nullptr
    const float* __restrict__ idxf,     // [N] as float
    const float* __restrict__ ema_cs,   // [1024]
    const float* __restrict__ ema_w,    // [1024][64]
    int*   __restrict__ counts_i,       // [1024]
    int*   __restrict__ cursor,         // [1024] zeroed
    int*   __restrict__ sorted,         // [131072]
    float* __restrict__ scal,           // [0]=sumsq [1]=nsum [2]=ent (0,1,2 zeroed; 0 set by argmin)
    float* __restrict__ out)
{
    cg::grid_group grid = cg::this_grid();
    __shared__ int   lstarts[KCODES];
    __shared__ int   lh[KCODES];        // hist, then global base
    __shared__ int   part[256];
    __shared__ float dwl[4 * 64];
    __shared__ float sred[256];

    const int t   = threadIdx.x;
    const int blk = blockIdx.x;         // 0..255

    float* o_loss  = out + QELEMS;
    float* o_perp  = out + QELEMS + 1;
    float* o_ncs   = out + QELEMS + 2 + NTOT;
    float* o_emaw  = o_ncs + KCODES;
    float* o_embed = o_emaw + KCODES * DIM;

    // Phase A: every block scans counts -> lstarts (exclusive)
    int4 c4 = *(const int4*)(counts_i + (t << 2));
    part[t] = c4.x + c4.y + c4.z + c4.w;
    {
        int tb = t << 2;
        lh[tb] = 0; lh[tb + 1] = 0; lh[tb + 2] = 0; lh[tb + 3] = 0;
    }
    __syncthreads();
    for (int off = 1; off < 256; off <<= 1) {
        int v   = part[t];
        int add = (t >= off) ? part[t - off] : 0;
        __syncthreads();
        part[t] = v + add;
        __syncthreads();
    }
    {
        int base = (t == 0) ? 0 : part[t - 1];
        int tb = t << 2;
        lstarts[tb]     = base;
        lstarts[tb + 1] = base + c4.x;
        lstarts[tb + 2] = base + c4.x + c4.y;
        lstarts[tb + 3] = base + c4.x + c4.y + c4.z;
    }
    __syncthreads();

    // Phase B: scatter this block's 512 rows with LDS aggregation
    int code0, code1, rank0, rank1;
    const int i0 = (blk << 9) + t;
    const int i1 = i0 + 256;
    code0 = (int)idxf[i0];
    rank0 = atomicAdd(&lh[code0], 1);
    code1 = (int)idxf[i1];
    rank1 = atomicAdd(&lh[code1], 1);
    __syncthreads();
    for (int k = t; k < KCODES; k += 256) {
        int cnt = lh[k];
        if (cnt) lh[k] = lstarts[k] + atomicAdd(&cursor[k], cnt);
    }
    __syncthreads();
    sorted[lh[code0] + rank0] = i0;
    sorted[lh[code1] + rank1] = i1;

    __threadfence();
    grid.sync();

    // Phase C: dw gather for codes k = blk + 256*q, q=0..3; ncs/nsum/ent partials
    const int wv = t >> 6, d = t & 63;
    for (int q = 0; q < 4; ++q) {
        int k  = blk + (q << 8);
        int s0 = lstarts[k];
        int s1 = (k == KCODES - 1) ? NTOT : lstarts[k + 1];
        float a0 = 0.f, a1 = 0.f, a2 = 0.f, a3 = 0.f;
        if (flat_x) {
            int m = s0 + wv;
            for (; m + 12 < s1; m += 16) {
                int r0 = sorted[m], r1 = sorted[m + 4];
                int r2 = sorted[m + 8], r3 = sorted[m + 12];
                a0 += flat_x[((size_t)r0 << 6) + d];
                a1 += flat_x[((size_t)r1 << 6) + d];
                a2 += flat_x[((size_t)r2 << 6) + d];
                a3 += flat_x[((size_t)r3 << 6) + d];
            }
            for (; m < s1; m += 4) a0 += flat_x[((size_t)sorted[m] << 6) + d];
        } else {
            for (int m = s0 + wv; m < s1; m += 4) {
                int r = sorted[m];
                int b = r >> 12, rem = r & 4095;
                a0 += in[b * 262144 + d * 4096 + rem];
            }
        }
        sred[t] = a0 + a1 + a2 + a3;
        __syncthreads();
        if (t < 64)
            dwl[(q << 6) + t] = sred[t] + sred[64 + t] + sred[128 + t] + sred[192 + t];
        __syncthreads();
    }
    if (t < 4) {
        int k = blk + (t << 8);
        float c   = (float)counts_i[k];
        float ncs = 0.99f * ema_cs[k] + 0.01f * c;
        o_ncs[k] = ncs;
        float p = c / (float)NTOT;
        atomicAdd(&scal[1], ncs);
        atomicAdd(&scal[2], p * logf(p + 1e-10f));
    }

    __threadfence();
    grid.sync();

    // Phase D: EMA weights + normalized embed for this block's 4 codes
    volatile float* vs = scal;
    float n = vs[1];
    float denom = n + (float)KCODES * 1e-5f;
    {
        int q = t >> 6, d2 = t & 63;
        int k = blk + (q << 8);
        float c   = (float)counts_i[k];
        float ncs = 0.99f * ema_cs[k] + 0.01f * c;
        float cs  = (ncs + 1e-5f) / denom * n;
        cs = fmaxf(cs, 1e-5f);
        float w = 0.99f * ema_w[(k << 6) + d2] + 0.01f * dwl[(q << 6) + d2];
        o_emaw[(k << 6) + d2]  = w;
        o_embed[(k << 6) + d2] = w / cs;
    }
    if (blk == 0 && t == 0) {
        o_loss[0] = 0.25f * vs[0] / (float)QELEMS;
        o_perp[0] = expf(-vs[2]);
    }
}

extern "C" void kernel_launch(void* const* d_in, const int* in_sizes, int n_in,
                              void* d_out, int out_size, void* d_ws, size_t ws_size,
                              hipStream_t stream) {
    const float* in     = (const float*)d_in[0];
    const float* embed  = (const float*)d_in[1];
    const float* ema_cs = (const float*)d_in[2];
    const float* ema_w  = (const float*)d_in[3];
    float* out = (float*)d_out;
    float* ws  = (float*)d_ws;

    int*   counts_i = (int*)ws;              // 1024
    float* scal     = ws + 1024;             // sumsq, nsum, ent
    int*   cursor   = (int*)ws + 1027;       // 1024
    float* enorm    = ws + 2052;             // 1024
    int*   sorted   = (int*)ws + 4104;       // 131072
    const bool use_flat = ws_size >= WS_NEED_FLAT;
    float* flat_x   = use_flat ? (ws + WS_FLAT_OFF) : (float*)0;
    float* o_idx    = out + QELEMS + 2;

    hipMemsetAsync(d_ws, 0, 2052 * sizeof(float), stream);  // counts+scal+cursor
    vq_enorm_kernel<<<4, 256, 0, stream>>>(embed, enorm);
    vq_argmin_kernel<<<1024, 256, 0, stream>>>(in, embed, enorm, out, o_idx,
                                               counts_i, scal, flat_x);
    {
        const float* flat_c = flat_x;
        void* args[] = {
            (void*)&in, (void*)&flat_c, (void*)&o_idx, (void*)&ema_cs,
            (void*)&ema_w, (void*)&counts_i, (void*)&cursor, (void*)&sorted,
            (void*)&scal, (void*)&out
        };
        hipLaunchCooperativeKernel((void*)vq_tail_kernel, dim3(256), dim3(256),
                                   args, 0, stream);
    }
}

// Round 6
// 426.886 us; speedup vs baseline: 4.6172x; 1.4786x over previous
//
#include <hip/hip_runtime.h>
#include <math.h>

#define KCODES 1024
#define DIM 64
#define NTOT 131072          // 32*64*64 rows
#define QELEMS 8388608       // 32*64*64*64
#define XSTR 68              // padded row stride (floats)

// ws layout (4B units):
//   0      counts_i [1024] int     (zeroed)
//   1024   scal [3]: sumsq,nsum,ent (zeroed)
//   1028   cursor [1024] int       (zeroed)
//   2052   dwacc [65536] float     (zeroed)
//   67588  enorm [1024] float
//   68612  keys  [131072] int  (code<<17 | row)
//   199684 flat_x [8388608] float  (optional)
#define WS_ZERO_FLOATS 67588
#define WS_FLAT_OFF 199684
#define WS_NEED_FLAT ((size_t)(WS_FLAT_OFF + QELEMS) * 4)

__global__ __launch_bounds__(256) void vq_enorm_kernel(const float* __restrict__ embed,
                                                       float* __restrict__ enorm) {
    int k = blockIdx.x * 256 + threadIdx.x;
    if (k < KCODES) {
        const float4* e4 = (const float4*)(embed + (k << 6));
        float s = 0.f;
#pragma unroll
        for (int j = 0; j < 16; ++j) {
            float4 v = e4[j];
            s += v.x * v.x + v.y * v.y + v.z * v.z + v.w * v.w;
        }
        enorm[k] = s;
    }
}

// Kernel A (FROZEN from R5): distances + argmin + fused epilogue.
__global__ __launch_bounds__(256, 2) void vq_argmin_kernel(
    const float* __restrict__ in,      // [32][64][64][64] NCHW
    const float* __restrict__ embed,   // [1024][64]
    const float* __restrict__ enorm,   // [1024]
    float* __restrict__ out_quant,     // [32][64][64][64]
    float* __restrict__ out_idx,       // [131072] (as float)
    int*   __restrict__ counts_i,      // [1024]
    float* __restrict__ sumsq,         // [1]
    float* __restrict__ flat_x)        // [131072][64] or nullptr
{
    __shared__ float xs[128 * XSTR];
    __shared__ float es[128 * XSTR];
    __shared__ float en[KCODES];

    const int t   = threadIdx.x;
    const int blk = blockIdx.x;        // 0..1023
    const int b   = blk >> 5;
    const int h0  = (blk & 31) << 1;
    const float* xb = in + b * 262144 + h0 * 64;

    for (int i = t; i < KCODES; i += 256) en[i] = enorm[i];

    {
        int hw = t & 127;
        int dh = t >> 7;
#pragma unroll
        for (int m = 0; m < 32; ++m) {
            int d = dh + (m << 1);
            xs[hw * XSTR + d] = xb[d * 4096 + hw];
        }
    }

    float4 pf[8];
    {
        const float4* eb = (const float4*)embed;
#pragma unroll
        for (int m = 0; m < 8; ++m) pf[m] = eb[t + (m << 8)];
    }
    __syncthreads();

    if (flat_x) {
        int row = t >> 1, half = t & 1;
        const float* src = xs + row * XSTR + (half << 5);
        float* dst = flat_x + ((size_t)blk << 13) + (row << 6) + (half << 5);
#pragma unroll
        for (int j = 0; j < 8; ++j)
            *(float4*)(dst + (j << 2)) = *(const float4*)(src + (j << 2));
    }

    const int rowg  = t & 15;
    const int codeg = t >> 4;
    float minv[8];
    int   mini[8];
#pragma unroll
    for (int i = 0; i < 8; ++i) { minv[i] = 3.4e38f; mini[i] = 0; }

    for (int tile = 0; tile < 8; ++tile) {
#pragma unroll
        for (int m = 0; m < 8; ++m) {
            int q = t + (m << 8);
            int c = q >> 4, dq = q & 15;
            *(float4*)(es + c * XSTR + (dq << 2)) = pf[m];
        }
        __syncthreads();

        if (tile < 7) {
            const float4* ebn = (const float4*)(embed + ((tile + 1) << 13));
#pragma unroll
            for (int m = 0; m < 8; ++m) pf[m] = ebn[t + (m << 8)];
        }

        float acc[8][8];
#pragma unroll
        for (int i = 0; i < 8; ++i)
#pragma unroll
            for (int j = 0; j < 8; ++j) acc[i][j] = 0.f;

#pragma unroll 2
        for (int d4 = 0; d4 < 16; ++d4) {
            float4 xv[8], ev[8];
#pragma unroll
            for (int i = 0; i < 8; ++i)
                xv[i] = *(const float4*)(xs + (rowg + (i << 4)) * XSTR + (d4 << 2));
#pragma unroll
            for (int j = 0; j < 8; ++j)
                ev[j] = *(const float4*)(es + (codeg + (j << 4)) * XSTR + (d4 << 2));
#pragma unroll
            for (int i = 0; i < 8; ++i)
#pragma unroll
                for (int j = 0; j < 8; ++j)
                    acc[i][j] += xv[i].x * ev[j].x + xv[i].y * ev[j].y
                               + xv[i].z * ev[j].z + xv[i].w * ev[j].w;
        }

        const int kbase = tile << 7;
#pragma unroll
        for (int j = 0; j < 8; ++j) {
            int c = kbase + codeg + (j << 4);
            float enc = en[c];
#pragma unroll
            for (int i = 0; i < 8; ++i) {
                float dist = enc - 2.0f * acc[i][j];
                if (dist < minv[i]) { minv[i] = dist; mini[i] = c; }
            }
        }
        __syncthreads();
    }

    int*   hist   = (int*)en;
    float* redv   = es;
    int*   redi   = (int*)(es + 2048);
    int*   idxs_s = (int*)(es + 4096);
    float* rsum   = es + 4224;

    for (int i = t; i < KCODES; i += 256) hist[i] = 0;
#pragma unroll
    for (int i = 0; i < 8; ++i) {
        int p = rowg + (i << 4);
        redv[codeg * 128 + p] = minv[i];
        redi[codeg * 128 + p] = mini[i];
    }
    __syncthreads();
    if (t < 128) {
        float bv = redv[t];
        int   bi = redi[t];
#pragma unroll
        for (int g = 1; g < 16; ++g) {
            float v  = redv[g * 128 + t];
            int   ii = redi[g * 128 + t];
            if (v < bv || (v == bv && ii < bi)) { bv = v; bi = ii; }
        }
        idxs_s[t] = bi;
        out_idx[(blk << 7) + t] = (float)bi;
        atomicAdd(&hist[bi], 1);
    }
    __syncthreads();
    for (int i = t; i < KCODES; i += 256) {
        int v = hist[i];
        if (v) atomicAdd(&counts_i[i], v);
    }

    {
        int hw = t & 127;
        int dh = t >> 7;
        int k  = idxs_s[hw];
        const float* eq = embed + (k << 6);
        float* ob = out_quant + b * 262144 + h0 * 64 + hw;
        float ls = 0.f;
#pragma unroll
        for (int m = 0; m < 32; ++m) {
            int d = dh + (m << 1);
            float q = eq[d];
            float x = xs[hw * XSTR + d];
            ob[d * 4096] = q;
            float e = q - x;
            ls += e * e;
        }
        rsum[t] = ls;
    }
    __syncthreads();
    for (int s = 128; s > 0; s >>= 1) {
        if (t < s) rsum[t] += rsum[t + s];
        __syncthreads();
    }
    if (t == 0) atomicAdd(sumsq, rsum[0]);
}

// Scatter with integrated redundant scan + LDS rank aggregation.
// 256 blocks x 256 threads; block handles 512 rows; writes packed keys.
__global__ __launch_bounds__(256) void vq_scatter_kernel(
    const float* __restrict__ idxf,
    const int*   __restrict__ counts_i,
    int* __restrict__ cursor,          // [1024] zeroed
    int* __restrict__ keys)            // [131072]
{
    __shared__ int lstarts[KCODES];
    __shared__ int lh[KCODES];
    __shared__ int part[256];
    const int t   = threadIdx.x;
    const int blk = blockIdx.x;

    int4 c4 = *(const int4*)(counts_i + (t << 2));
    part[t] = c4.x + c4.y + c4.z + c4.w;
    {
        int tb = t << 2;
        lh[tb] = 0; lh[tb + 1] = 0; lh[tb + 2] = 0; lh[tb + 3] = 0;
    }
    __syncthreads();
    for (int off = 1; off < 256; off <<= 1) {
        int v   = part[t];
        int add = (t >= off) ? part[t - off] : 0;
        __syncthreads();
        part[t] = v + add;
        __syncthreads();
    }
    {
        int base = (t == 0) ? 0 : part[t - 1];
        int tb = t << 2;
        lstarts[tb]     = base;
        lstarts[tb + 1] = base + c4.x;
        lstarts[tb + 2] = base + c4.x + c4.y;
        lstarts[tb + 3] = base + c4.x + c4.y + c4.z;
    }
    __syncthreads();

    const int i0 = (blk << 9) + t;
    const int i1 = i0 + 256;
    int code0 = (int)idxf[i0];
    int rank0 = atomicAdd(&lh[code0], 1);
    int code1 = (int)idxf[i1];
    int rank1 = atomicAdd(&lh[code1], 1);
    __syncthreads();
    for (int k = t; k < KCODES; k += 256) {
        int cnt = lh[k];
        if (cnt) lh[k] = lstarts[k] + atomicAdd(&cursor[k], cnt);
    }
    __syncthreads();
    keys[lh[code0] + rank0] = (code0 << 17) | i0;
    keys[lh[code1] + rank1] = (code1 << 17) | i1;
}

// Balanced dw: 256 blocks x 4 waves; each wave owns 128 consecutive sorted
// positions. Segmented accumulate, one wave-wide atomic flush per code boundary.
__global__ __launch_bounds__(256) void vq_dw_kernel(
    const float* __restrict__ flat_x,  // [N][64]
    const int*   __restrict__ keys,    // [131072] code<<17 | row
    float* __restrict__ dwacc)         // [1024][64] zeroed
{
    const int t   = threadIdx.x;
    const int blk = blockIdx.x;
    const int wv  = t >> 6, d = t & 63;
    const int base = (blk << 9) + (wv << 7);   // 128 rows per wave

    int key   = keys[base];
    int c_cur = key >> 17;
    int r     = key & 0x1FFFF;
    float acc = 0.f;
#pragma unroll 4
    for (int m = 0; m < 128; ++m) {
        float x = flat_x[((size_t)r << 6) + d];
        int nkey = (m < 127) ? keys[base + m + 1] : -1;
        int c_n  = nkey >> 17;
        int r_n  = nkey & 0x1FFFF;
        acc += x;
        if (c_n != c_cur) {
            atomicAdd(&dwacc[(c_cur << 6) + d], acc);
            acc = 0.f;
            c_cur = c_n;
        }
        r = r_n;
    }
}

// dw fallback from NCHW when flat_x scratch unavailable (uncoalesced).
__global__ __launch_bounds__(256) void vq_dw_nchw_kernel(
    const float* __restrict__ in,
    const int*   __restrict__ keys,
    float* __restrict__ dwacc)
{
    const int t   = threadIdx.x;
    const int blk = blockIdx.x;
    const int wv  = t >> 6, d = t & 63;
    const int base = (blk << 9) + (wv << 7);

    int key   = keys[base];
    int c_cur = key >> 17;
    int r     = key & 0x1FFFF;
    float acc = 0.f;
    for (int m = 0; m < 128; ++m) {
        int b = r >> 12, rem = r & 4095;
        float x = in[b * 262144 + d * 4096 + rem];
        int nkey = (m < 127) ? keys[base + m + 1] : -1;
        int c_n  = nkey >> 17;
        int r_n  = nkey & 0x1FFFF;
        acc += x;
        if (c_n != c_cur) {
            atomicAdd(&dwacc[(c_cur << 6) + d], acc);
            acc = 0.f;
            c_cur = c_n;
        }
        r = r_n;
    }
}

// finalize A: 4 blocks; per-code ncs + entropy/nsum partials.
__global__ __launch_bounds__(256) void vq_fin_a_kernel(
    const float* __restrict__ ema_cs,
    const int*   __restrict__ counts_i,
    float* __restrict__ scal,           // [1]=nsum [2]=ent
    float* __restrict__ out)
{
    __shared__ float r1[256], r2[256];
    const int t = threadIdx.x;
    const int k = blockIdx.x * 256 + t;
    float* o_ncs = out + QELEMS + 2 + NTOT;

    float c   = (float)counts_i[k];
    float ncs = 0.99f * ema_cs[k] + 0.01f * c;
    o_ncs[k] = ncs;
    float p = c / (float)NTOT;
    r1[t] = ncs;
    r2[t] = p * logf(p + 1e-10f);
    __syncthreads();
    for (int s = 128; s > 0; s >>= 1) {
        if (t < s) { r1[t] += r1[t + s]; r2[t] += r2[t + s]; }
        __syncthreads();
    }
    if (t == 0) {
        atomicAdd(&scal[1], r1[0]);
        atomicAdd(&scal[2], r2[0]);
    }
}

// finalize B: 32 blocks; EMA weights + normalized embed; scalars by block 0.
__global__ __launch_bounds__(256) void vq_fin_b_kernel(
    const float* __restrict__ ema_cs,
    const float* __restrict__ ema_w,
    const int*   __restrict__ counts_i,
    const float* __restrict__ dwacc,
    const float* __restrict__ scal,
    float* __restrict__ out)
{
    const int t = threadIdx.x;
    float* o_loss  = out + QELEMS;
    float* o_perp  = out + QELEMS + 1;
    float* o_ncs   = out + QELEMS + 2 + NTOT;
    float* o_emaw  = o_ncs + KCODES;
    float* o_embed = o_emaw + KCODES * DIM;

    float n = scal[1];
    float denom = n + (float)KCODES * 1e-5f;
#pragma unroll
    for (int u = 0; u < 8; ++u) {
        int i = (blockIdx.x << 11) + (u << 8) + t;   // 65536 total
        int k = i >> 6;
        float c   = (float)counts_i[k];
        float ncs = 0.99f * ema_cs[k] + 0.01f * c;
        float cs  = (ncs + 1e-5f) / denom * n;
        cs = fmaxf(cs, 1e-5f);
        float w = 0.99f * ema_w[i] + 0.01f * dwacc[i];
        o_emaw[i]  = w;
        o_embed[i] = w / cs;
    }
    if (blockIdx.x == 0 && t == 0) {
        o_loss[0] = 0.25f * scal[0] / (float)QELEMS;
        o_perp[0] = expf(-scal[2]);
    }
}

extern "C" void kernel_launch(void* const* d_in, const int* in_sizes, int n_in,
                              void* d_out, int out_size, void* d_ws, size_t ws_size,
                              hipStream_t stream) {
    const float* in     = (const float*)d_in[0];
    const float* embed  = (const float*)d_in[1];
    const float* ema_cs = (const float*)d_in[2];
    const float* ema_w  = (const float*)d_in[3];
    float* out = (float*)d_out;
    float* ws  = (float*)d_ws;

    int*   counts_i = (int*)ws;              // 1024
    float* scal     = ws + 1024;             // 3
    int*   cursor   = (int*)ws + 1028;       // 1024
    float* dwacc    = ws + 2052;             // 65536
    float* enorm    = ws + 67588;            // 1024
    int*   keys     = (int*)ws + 68612;      // 131072
    const bool use_flat = ws_size >= WS_NEED_FLAT;
    float* flat_x   = use_flat ? (ws + WS_FLAT_OFF) : (float*)0;
    float* o_idx    = out + QELEMS + 2;

    hipMemsetAsync(d_ws, 0, (size_t)WS_ZERO_FLOATS * sizeof(float), stream);
    vq_enorm_kernel<<<4, 256, 0, stream>>>(embed, enorm);
    vq_argmin_kernel<<<1024, 256, 0, stream>>>(in, embed, enorm, out, o_idx,
                                               counts_i, scal, flat_x);
    vq_scatter_kernel<<<256, 256, 0, stream>>>(o_idx, counts_i, cursor, keys);
    if (use_flat)
        vq_dw_kernel<<<256, 256, 0, stream>>>(flat_x, keys, dwacc);
    else
        vq_dw_nchw_kernel<<<256, 256, 0, stream>>>(in, keys, dwacc);
    vq_fin_a_kernel<<<4, 256, 0, stream>>>(ema_cs, counts_i, scal, out);
    vq_fin_b_kernel<<<32, 256, 0, stream>>>(ema_cs, ema_w, counts_i, dwacc, scal, out);
}